// Round 2
// 6769.237 us; speedup vs baseline: 1.0184x; 1.0184x over previous
//
#include <hip/hip_runtime.h>
#include <hip/hip_cooperative_groups.h>
#include <math.h>

namespace cg = cooperative_groups;

#define Q 2048
#define NOBS 8192
#define NSTEPS 32
#define NBLK 256

// ---------------------------------------------------------------------------
// IF-level coherent load: ONLY for the atomically-accumulated scalars.
__device__ __forceinline__ float coh_load4(const float* p) {
  unsigned v = __hip_atomic_load((const unsigned*)p, __ATOMIC_RELAXED,
                                 __HIP_MEMORY_SCOPE_AGENT);
  return __uint_as_float(v);
}

// ---------------------------------------------------------------------------
__device__ __forceinline__ float block_sum256(float v, volatile float* red) {
  int tid = threadIdx.x;
#pragma unroll
  for (int o = 32; o > 0; o >>= 1) v += __shfl_down(v, o);
  __syncthreads();
  if ((tid & 63) == 0) red[tid >> 6] = v;
  __syncthreads();
  return red[0] + red[1] + red[2] + red[3];
}

// ---------------------------------------------------------------------------
__global__ __launch_bounds__(256) void obs_kernel(
    const float* __restrict__ yt, const float* __restrict__ yp,
    const int* __restrict__ zidx, const float* __restrict__ s2e_p,
    const float* __restrict__ s2b_p, float* __restrict__ t,
    int* __restrict__ cnt, float* __restrict__ scal) {
  __shared__ float red[4];
  int i = blockIdx.x * 256 + threadIdx.x;
  float s2e = s2e_p[0], s2b = s2b_p[0];
  float sig2 = s2e + s2b;
  float r = yt[i] - yp[i];
  float e = erff(r * rsqrtf(2.0f * sig2));
  float u = 0.5f * (e + 1.0f);
  u = fminf(fmaxf(u, 1e-5f), 1.0f - 1e-5f);
  float m = erfinvf(2.0f * u - 1.0f) * 1.4142135623730951f;
  float slp = -0.5f * logf(2.0f * 3.14159265358979f * sig2) - r * r / (2.0f * sig2);
  int z = zidx[i];
  atomicAdd(&t[z], m);
  atomicAdd(&cnt[z], 1);
  float s1 = block_sum256(slp, red);
  float s2 = block_sum256(m * m, red);
  if (threadIdx.x == 0) {
    atomicAdd(&scal[0], s1);   // sum_log_pdf
    atomicAdd(&scal[1], s2);   // m'm
  }
}

// ---------------------------------------------------------------------------
__global__ __launch_bounds__(256) void build_G(
    const float* __restrict__ dist, const float* __restrict__ s2e_p,
    const float* __restrict__ s2b_p, const float* __restrict__ ell_p,
    const int* __restrict__ cnt, float* __restrict__ G) {
  int idx = blockIdx.x * 256 + threadIdx.x;
  int j = idx >> 11;
  int k = idx & (Q - 1);
  float s2e = s2e_p[0], s2b = s2b_p[0], ell = ell_p[0];
  float sig2 = s2e + s2b;
  float a = (s2b / sig2) * expf(-dist[idx] / (2.0f * ell));
  float g = sqrtf((float)cnt[j] * (float)cnt[k]) * a;
  if (j == k) g += s2e / sig2;
  G[idx] = g;
}

// ---------------------------------------------------------------------------
__global__ __launch_bounds__(256) void matvec_kernel(
    const float* __restrict__ dist, const float* __restrict__ s2e_p,
    const float* __restrict__ s2b_p, const float* __restrict__ ell_p,
    const int* __restrict__ cnt, const float* __restrict__ t,
    float* __restrict__ z, float* __restrict__ scal) {
  __shared__ float red[4];
  int j = blockIdx.x;
  float s2e = s2e_p[0], s2b = s2b_p[0], ell = ell_p[0];
  float sig2 = s2e + s2b;
  float inv2ell = 1.0f / (2.0f * ell);
  float s = 0.0f;
  const float* drow = dist + (size_t)j * Q;
  for (int k = threadIdx.x; k < Q; k += 256) s += expf(-drow[k] * inv2ell) * t[k];
  float tot = block_sum256(s, red);
  if (threadIdx.x == 0) {
    float wj = (s2b / sig2) * tot;
    z[j] = sqrtf((float)cnt[j]) * wj;   // b = W^{1/2} w
    atomicAdd(&scal[2], t[j] * wj);     // t.w
  }
}

// ---------------------------------------------------------------------------
// Wave-level 64x64 Cholesky, rows in registers; CACHED loads, stride Q.
__device__ __forceinline__ void wave_chol64(const float* src, float* rr) {
  int lane = threadIdx.x & 63;
  const float* row = src + (size_t)lane * Q;
#pragma unroll
  for (int k4 = 0; k4 < 16; ++k4) {
    float4 v = *(const float4*)(row + k4 * 4);
    rr[k4 * 4 + 0] = v.x; rr[k4 * 4 + 1] = v.y;
    rr[k4 * 4 + 2] = v.z; rr[k4 * 4 + 3] = v.w;
  }
#pragma unroll
  for (int j = 0; j < 64; ++j) {
    float vjj = __shfl(rr[j], j);
    float invd = rsqrtf(vjj);
    float lij = rr[j] * invd;   // lane j gets sqrt(vjj)
    rr[j] = lij;
#pragma unroll
    for (int k = 0; k < 64; ++k)
      if (k > j) rr[k] -= lij * __shfl(lij, k);
  }
}

// ---------------------------------------------------------------------------
// One 64x64 trailing-update tile: G[R0:,C0:] -= P * Qt^T (panel at col j0).
// All global traffic is plain cached float4.
__device__ __forceinline__ void syrk_tile(float* __restrict__ G, int j0,
                                          int R0, int C0, float* shA,
                                          float* shB) {
  int tid = threadIdx.x;
#pragma unroll
  for (int it = 0; it < 4; ++it) {
    int idx = it * 256 + tid;           // 1024 16B chunks
    int r = idx >> 4, c4 = (idx & 15) * 4;
    float4 v = *(const float4*)(G + (size_t)(R0 + r) * Q + j0 + c4);
    shA[(c4 + 0) * 68 + r] = v.x; shA[(c4 + 1) * 68 + r] = v.y;
    shA[(c4 + 2) * 68 + r] = v.z; shA[(c4 + 3) * 68 + r] = v.w;
    float4 u = *(const float4*)(G + (size_t)(C0 + r) * Q + j0 + c4);
    shB[(c4 + 0) * 68 + r] = u.x; shB[(c4 + 1) * 68 + r] = u.y;
    shB[(c4 + 2) * 68 + r] = u.z; shB[(c4 + 3) * 68 + r] = u.w;
  }
  __syncthreads();
  int tx = tid & 15, ty = tid >> 4;
  float acc[4][4] = {{0.f}};
  for (int p = 0; p < 64; ++p) {
    float4 a4 = *(const float4*)&shA[p * 68 + ty * 4];
    float4 b4 = *(const float4*)&shB[p * 68 + tx * 4];
    float av[4] = {a4.x, a4.y, a4.z, a4.w};
    float bv[4] = {b4.x, b4.y, b4.z, b4.w};
#pragma unroll
    for (int i = 0; i < 4; ++i)
#pragma unroll
      for (int jj = 0; jj < 4; ++jj) acc[i][jj] += av[i] * bv[jj];
  }
#pragma unroll
  for (int i = 0; i < 4; ++i) {
    float* gp = G + (size_t)(R0 + ty * 4 + i) * Q + C0 + tx * 4;
    float4 g = *(const float4*)gp;
    g.x -= acc[i][0]; g.y -= acc[i][1];
    g.z -= acc[i][2]; g.w -= acc[i][3];
    *(float4*)gp = g;
  }
}

// ---------------------------------------------------------------------------
// Blocked Cholesky with RHS carried as a virtual row; cooperative grid sync
// (runtime-managed release/acquire cache maintenance); next-step diag tile
// factored by block 0 during phase C (lookahead).
__global__ __launch_bounds__(256, 1) void chol_coop(
    float* __restrict__ G, float* __restrict__ z, float* __restrict__ scal,
    float* __restrict__ ldstage, const float* __restrict__ s2e_p,
    const float* __restrict__ s2b_p, float* __restrict__ out) {
  cg::grid_group grid = cg::this_grid();
  __shared__ __align__(16) float shA[64 * 68];
  __shared__ __align__(16) float shB[64 * 68];
  __shared__ float z1s[64];
  __shared__ float red[256];
  int tid = threadIdx.x;
  int lane = tid & 63, wv = tid >> 6;
  int bx = blockIdx.x;

  for (int s = 0; s < NSTEPS; ++s) {
    int j0 = s * 64;
    int ntr = Q - j0 - 64;
    int nb = ntr >> 6;
    int Rtot = ntr + 1;   // trailing rows + z row

    // ---- obtain factored diag tile into shA (stride 65, lower) ----
    if (s == 0) {
      if (wv == 0) {
        float rr[64];
        wave_chol64(G, rr);
        float dv = 1.0f;
#pragma unroll
        for (int k = 0; k < 64; ++k) {
          if (k <= lane) shA[lane * 65 + k] = rr[k];
          if (k == lane) dv = rr[k];
        }
        if (bx == 0) {
          float lg = logf(dv);
#pragma unroll
          for (int o = 32; o > 0; o >>= 1) lg += __shfl_down(lg, o);
          if (lane == 0) atomicAdd(&scal[3], lg);
        }
      }
    } else {
#pragma unroll
      for (int it = 0; it < 4; ++it) {
        int idx = it * 256 + tid;        // 1024 16B chunks
        int r = idx >> 4, c4 = (idx & 15) * 4;
        float4 v = *(const float4*)(ldstage + r * 64 + c4);
        shA[r * 65 + c4 + 0] = v.x; shA[r * 65 + c4 + 1] = v.y;
        shA[r * 65 + c4 + 2] = v.z; shA[r * 65 + c4 + 3] = v.w;
      }
    }
    __syncthreads();

    // ---- phase B: TRSM trailing rows + z row ----
    {
      float dinv = 1.0f / shA[lane * 65 + lane];
      int gw = bx * 4 + wv;
      for (int ri = gw; ri < Rtot; ri += NBLK * 4) {
        int r = j0 + 64 + ri;
        float* grow = (r < Q) ? (G + (size_t)r * Q + j0) : (z + j0);
        float a = grow[lane];
        for (int p = 0; p < 64; ++p) {
          float xp = __shfl(a, p) * __shfl(dinv, p);
          if (lane > p) a -= xp * shA[lane * 65 + p];
        }
        grow[lane] = a * dinv;
      }
    }
    grid.sync();

    // ---- phase C: trailing SYRK + z update; block 0 preps next diag ----
    if (nb > 0) {
      int ntri = nb * (nb + 1) / 2;
      if (bx == 0) {
        int D0 = j0 + 64;
        syrk_tile(G, j0, D0, D0, shA, shB);   // update next diag tile
        __syncthreads();
        // intra-block cross-wave handoff through global memory
        __builtin_amdgcn_fence(__ATOMIC_ACQUIRE, "workgroup");
        if (wv == 0) {
          float rr[64];
          wave_chol64(G + (size_t)D0 * Q + D0, rr);
          float dv = 1.0f;
#pragma unroll
          for (int k4 = 0; k4 < 16; ++k4) {
            float4 st;
            st.x = rr[k4 * 4 + 0]; st.y = rr[k4 * 4 + 1];
            st.z = rr[k4 * 4 + 2]; st.w = rr[k4 * 4 + 3];
            *(float4*)(ldstage + lane * 64 + k4 * 4) = st;
#pragma unroll
            for (int j = 0; j < 4; ++j)
              if (k4 * 4 + j == lane) dv = rr[k4 * 4 + j];
          }
          float lg = logf(dv);
#pragma unroll
          for (int o = 32; o > 0; o >>= 1) lg += __shfl_down(lg, o);
          if (lane == 0) atomicAdd(&scal[3], lg);
        }
      } else {
        int njobs = ntri + nb;
        for (int job = bx - 1; job < njobs; job += NBLK - 1) {
          __syncthreads();
          if (job < ntri) {
            if (job == 0) continue;   // diag tile: block 0's
            int bi = (int)((sqrtf(8.0f * (float)job + 1.0f) - 1.0f) * 0.5f);
            while ((bi + 1) * (bi + 2) / 2 <= job) ++bi;
            while (bi * (bi + 1) / 2 > job) --bi;
            int bk = job - bi * (bi + 1) / 2;
            syrk_tile(G, j0, j0 + 64 + bi * 64, j0 + 64 + bk * 64, shA, shB);
          } else {
            int bk = job - ntri;
            int C0 = j0 + 64 + bk * 64;
            if (tid < 64) z1s[tid] = z[j0 + tid];
            __syncthreads();
            int rw = tid >> 2, part = tid & 3;
            const float* Lr = G + (size_t)(C0 + rw) * Q + j0;
            float ssum = 0.f;
            for (int p = part; p < 64; p += 4) ssum += Lr[p] * z1s[p];
            ssum += __shfl_down(ssum, 2);
            ssum += __shfl_down(ssum, 1);
            if (part == 0) {
              z[C0 + rw] -= ssum;
            }
          }
        }
      }
    }
    grid.sync();
  }

  // ---- final assembly (block 0) ----
  if (bx == 0) {
    float bv = 0.f;
    for (int i = tid; i < Q; i += 256) {
      float zi = z[i];
      bv += zi * zi;
    }
    float bvs = block_sum256(bv, red);
    if (tid == 0) {
      float s2e = s2e_p[0], s2b = s2b_p[0];
      float sig2 = s2e + s2b;
      float c = s2e / sig2;
      float slp = coh_load4(&scal[0]), mtm = coh_load4(&scal[1]);
      float tw = coh_load4(&scal[2]), sl = coh_load4(&scal[3]);
      float tty = (tw - bvs) / c;          // t' y
      float mrm = (mtm - tty) / c;         // m' R^{-1} m
      float logdetR = (float)(NOBS - Q) * logf(c) + 2.0f * sl;
      out[0] = 0.5f * logdetR + 0.5f * mrm - 0.5f * mtm + 0.5f * slp;
    }
  }
}

// ---------------------------------------------------------------------------
extern "C" void kernel_launch(void* const* d_in, const int* in_sizes, int n_in,
                              void* d_out, int out_size, void* d_ws, size_t ws_size,
                              hipStream_t stream) {
  const float* yt   = (const float*)d_in[0];
  const float* yp   = (const float*)d_in[1];
  const int*   zidx = (const int*)d_in[2];
  const float* dist = (const float*)d_in[3];
  const float* s2e  = (const float*)d_in[4];
  const float* s2b  = (const float*)d_in[5];
  const float* ell  = (const float*)d_in[6];

  float* ws   = (float*)d_ws;
  float* G    = ws;                         // Q*Q floats = 16 MB
  float* z    = ws + (size_t)Q * Q;         // Q
  float* t    = z + Q;                      // Q
  int*   cnt  = (int*)(t + Q);              // Q ints
  float* scal = t + 2 * Q;                  // 8: slp, mtm, tw, sumlogL
  float* ldstage = scal + 8;                // 64*64 staged diag factor

  // zero t, cnt, scal
  hipMemsetAsync(t, 0, (2 * Q + 8) * sizeof(float), stream);

  obs_kernel<<<NOBS / 256, 256, 0, stream>>>(yt, yp, zidx, s2e, s2b, t, cnt, scal);
  build_G<<<(Q * Q) / 256, 256, 0, stream>>>(dist, s2e, s2b, ell, cnt, G);
  matvec_kernel<<<Q, 256, 0, stream>>>(dist, s2e, s2b, ell, cnt, t, z, scal);

  float* outp = (float*)d_out;
  void* args[] = {&G, &z, &scal, &ldstage, &s2e, &s2b, &outp};
  hipLaunchCooperativeKernel((void*)chol_coop, dim3(NBLK), dim3(256),
                             args, 0, stream);
}

// Round 3
// 1070.397 us; speedup vs baseline: 6.4403x; 6.3240x over previous
//
#include <hip/hip_runtime.h>
#include <math.h>

#define Q 2048
#define NOBS 8192
#define NSTEPS 32

// ---------------------------------------------------------------------------
// readlane broadcast: lane index is a compile-time literal after unrolling,
// so this is a VALU->SGPR read (no LDS/ds_bpermute 120cy latency).
__device__ __forceinline__ float rl(float v, int l) {
  return __int_as_float(__builtin_amdgcn_readlane(__float_as_int(v), l));
}

// ---------------------------------------------------------------------------
__device__ __forceinline__ float block_sum256(float v, volatile float* red) {
  int tid = threadIdx.x;
#pragma unroll
  for (int o = 32; o > 0; o >>= 1) v += __shfl_down(v, o);
  __syncthreads();
  if ((tid & 63) == 0) red[tid >> 6] = v;
  __syncthreads();
  return red[0] + red[1] + red[2] + red[3];
}

// ---------------------------------------------------------------------------
// In-register 64x64 Cholesky, one wave, lane = row. Broadcasts via readlane.
// Returns lane j's diag sqrt (for logdet).
__device__ __forceinline__ float chol64_reg(float rr[64], int lane) {
  float dv = 1.0f;
#pragma unroll
  for (int j = 0; j < 64; ++j) {
    float vjj = rl(rr[j], j);
    float invd = rsqrtf(vjj);
    float lij = rr[j] * invd;   // lane j gets sqrt(vjj)
    rr[j] = lij;
    if (lane == j) dv = lij;
#pragma unroll
    for (int k = j + 1; k < 64; ++k) rr[k] -= lij * rl(lij, k);
  }
  return dv;
}

// ---------------------------------------------------------------------------
__global__ __launch_bounds__(256) void obs_kernel(
    const float* __restrict__ yt, const float* __restrict__ yp,
    const int* __restrict__ zidx, const float* __restrict__ s2e_p,
    const float* __restrict__ s2b_p, float* __restrict__ t,
    int* __restrict__ cnt, float* __restrict__ scal) {
  __shared__ float red[4];
  int i = blockIdx.x * 256 + threadIdx.x;
  float s2e = s2e_p[0], s2b = s2b_p[0];
  float sig2 = s2e + s2b;
  float r = yt[i] - yp[i];
  float e = erff(r * rsqrtf(2.0f * sig2));
  float u = 0.5f * (e + 1.0f);
  u = fminf(fmaxf(u, 1e-5f), 1.0f - 1e-5f);
  float m = erfinvf(2.0f * u - 1.0f) * 1.4142135623730951f;
  float slp = -0.5f * logf(2.0f * 3.14159265358979f * sig2) - r * r / (2.0f * sig2);
  int z = zidx[i];
  atomicAdd(&t[z], m);
  atomicAdd(&cnt[z], 1);
  float s1 = block_sum256(slp, red);
  float s2 = block_sum256(m * m, red);
  if (threadIdx.x == 0) {
    atomicAdd(&scal[0], s1);   // sum_log_pdf
    atomicAdd(&scal[1], s2);   // m'm
  }
}

// ---------------------------------------------------------------------------
__global__ __launch_bounds__(256) void build_G(
    const float* __restrict__ dist, const float* __restrict__ s2e_p,
    const float* __restrict__ s2b_p, const float* __restrict__ ell_p,
    const int* __restrict__ cnt, float* __restrict__ G) {
  int idx = blockIdx.x * 256 + threadIdx.x;
  int j = idx >> 11;
  int k = idx & (Q - 1);
  float s2e = s2e_p[0], s2b = s2b_p[0], ell = ell_p[0];
  float sig2 = s2e + s2b;
  float a = (s2b / sig2) * expf(-dist[idx] / (2.0f * ell));
  float g = sqrtf((float)cnt[j] * (float)cnt[k]) * a;
  if (j == k) g += s2e / sig2;
  G[idx] = g;
}

// ---------------------------------------------------------------------------
__global__ __launch_bounds__(256) void matvec_kernel(
    const float* __restrict__ dist, const float* __restrict__ s2e_p,
    const float* __restrict__ s2b_p, const float* __restrict__ ell_p,
    const int* __restrict__ cnt, const float* __restrict__ t,
    float* __restrict__ z, float* __restrict__ scal) {
  __shared__ float red[4];
  int j = blockIdx.x;
  float s2e = s2e_p[0], s2b = s2b_p[0], ell = ell_p[0];
  float sig2 = s2e + s2b;
  float inv2ell = 1.0f / (2.0f * ell);
  float s = 0.0f;
  const float* drow = dist + (size_t)j * Q;
  for (int k = threadIdx.x; k < Q; k += 256) s += expf(-drow[k] * inv2ell) * t[k];
  float tot = block_sum256(s, red);
  if (threadIdx.x == 0) {
    float wj = (s2b / sig2) * tot;
    z[j] = sqrtf((float)cnt[j]) * wj;   // b = W^{1/2} w
    atomicAdd(&scal[2], t[j] * wj);     // t.w
  }
}

// ---------------------------------------------------------------------------
// Factor the first 64x64 diag tile of G into dstage; accumulate logdet.
__global__ __launch_bounds__(64) void potrf_first(
    const float* __restrict__ G, float* __restrict__ dstage,
    float* __restrict__ scal) {
  int lane = threadIdx.x;
  float rr[64];
  const float* row = G + (size_t)lane * Q;
#pragma unroll
  for (int k4 = 0; k4 < 16; ++k4) {
    float4 v = *(const float4*)(row + k4 * 4);
    rr[k4 * 4 + 0] = v.x; rr[k4 * 4 + 1] = v.y;
    rr[k4 * 4 + 2] = v.z; rr[k4 * 4 + 3] = v.w;
  }
  float dv = chol64_reg(rr, lane);
#pragma unroll
  for (int k4 = 0; k4 < 16; ++k4) {
    float4 st;
    st.x = rr[k4 * 4 + 0]; st.y = rr[k4 * 4 + 1];
    st.z = rr[k4 * 4 + 2]; st.w = rr[k4 * 4 + 3];
    *(float4*)(dstage + lane * 64 + k4 * 4) = st;
  }
  float lg = logf(dv);
#pragma unroll
  for (int o = 32; o > 0; o >>= 1) lg += __shfl_down(lg, o);
  if (lane == 0) atomicAdd(&scal[3], lg);
}

// ---------------------------------------------------------------------------
// TRSM of the panel below the staged diag factor (+ z as a virtual row).
// One row per wave; readlane-based solve (serial chain ~64 x ~20cy).
__global__ __launch_bounds__(256) void trsm_step(
    float* __restrict__ G, float* __restrict__ z,
    const float* __restrict__ dstage, int j0, int Rtot) {
  __shared__ float shA[64 * 65];
  int tid = threadIdx.x;
#pragma unroll
  for (int it = 0; it < 4; ++it) {
    int idx = it * 256 + tid;          // 1024 chunks of 4 floats
    int r = idx >> 4, c = (idx & 15) * 4;
    float4 v = *(const float4*)(dstage + r * 64 + c);
    shA[r * 65 + c + 0] = v.x; shA[r * 65 + c + 1] = v.y;
    shA[r * 65 + c + 2] = v.z; shA[r * 65 + c + 3] = v.w;
  }
  __syncthreads();
  int lane = tid & 63, wv = tid >> 6;
  int ri = blockIdx.x * 4 + wv;
  if (ri >= Rtot) return;
  int r = j0 + 64 + ri;
  float* grow = (r < Q) ? (G + (size_t)r * Q + j0) : (z + j0);
  float a = grow[lane];
  float myinv = 1.0f / shA[lane * 65 + lane];
#pragma unroll
  for (int p = 0; p < 64; ++p) {
    float xp = rl(a, p) * rl(myinv, p);
    if (lane > p) a -= xp * shA[lane * 65 + p];
  }
  grow[lane] = a * myinv;
}

// ---------------------------------------------------------------------------
// One 64x64 trailing-update tile: G[R0:,C0:] -= P * Qt^T (panel at col j0).
__device__ __forceinline__ void syrk_tile(float* __restrict__ G, int j0,
                                          int R0, int C0, float* shA,
                                          float* shB) {
  int tid = threadIdx.x;
#pragma unroll
  for (int it = 0; it < 4; ++it) {
    int idx = it * 256 + tid;           // 1024 16B chunks
    int r = idx >> 4, c4 = (idx & 15) * 4;
    float4 v = *(const float4*)(G + (size_t)(R0 + r) * Q + j0 + c4);
    shA[(c4 + 0) * 68 + r] = v.x; shA[(c4 + 1) * 68 + r] = v.y;
    shA[(c4 + 2) * 68 + r] = v.z; shA[(c4 + 3) * 68 + r] = v.w;
    float4 u = *(const float4*)(G + (size_t)(C0 + r) * Q + j0 + c4);
    shB[(c4 + 0) * 68 + r] = u.x; shB[(c4 + 1) * 68 + r] = u.y;
    shB[(c4 + 2) * 68 + r] = u.z; shB[(c4 + 3) * 68 + r] = u.w;
  }
  __syncthreads();
  int tx = tid & 15, ty = tid >> 4;
  float acc[4][4] = {{0.f}};
  for (int p = 0; p < 64; ++p) {
    float4 a4 = *(const float4*)&shA[p * 68 + ty * 4];
    float4 b4 = *(const float4*)&shB[p * 68 + tx * 4];
    float av[4] = {a4.x, a4.y, a4.z, a4.w};
    float bv[4] = {b4.x, b4.y, b4.z, b4.w};
#pragma unroll
    for (int i = 0; i < 4; ++i)
#pragma unroll
      for (int jj = 0; jj < 4; ++jj) acc[i][jj] += av[i] * bv[jj];
  }
#pragma unroll
  for (int i = 0; i < 4; ++i) {
    float* gp = G + (size_t)(R0 + ty * 4 + i) * Q + C0 + tx * 4;
    float4 g = *(const float4*)gp;
    g.x -= acc[i][0]; g.y -= acc[i][1];
    g.z -= acc[i][2]; g.w -= acc[i][3];
    *(float4*)gp = g;
  }
}

// ---------------------------------------------------------------------------
// Per-step trailing work, one job per block:
//   job 0            : lookahead — update NEXT diag tile and factor it into
//                      dstage (never written back to G; not needed again).
//   job in [1,ntri)  : strict-lower / off-diag trailing SYRK tiles.
//   job in [ntri, ..): z forward-substitution updates per trailing block.
__global__ __launch_bounds__(256) void syrk_step(
    float* __restrict__ G, float* __restrict__ z, float* __restrict__ dstage,
    float* __restrict__ scal, int j0, int ntri) {
  __shared__ __align__(16) float shA[64 * 68];
  __shared__ __align__(16) float shB[64 * 68];
  __shared__ float z1s[64];
  int tid = threadIdx.x;
  int bx = blockIdx.x;

  if (bx == 0) {
    int D0 = j0 + 64;
    // stage panel rows D0..D0+64, cols j0..j0+64 (transposed) into shA
#pragma unroll
    for (int it = 0; it < 4; ++it) {
      int idx = it * 256 + tid;
      int r2 = idx >> 4, c4 = (idx & 15) * 4;
      float4 v = *(const float4*)(G + (size_t)(D0 + r2) * Q + j0 + c4);
      shA[(c4 + 0) * 68 + r2] = v.x; shA[(c4 + 1) * 68 + r2] = v.y;
      shA[(c4 + 2) * 68 + r2] = v.z; shA[(c4 + 3) * 68 + r2] = v.w;
    }
    __syncthreads();
    int tx = tid & 15, ty = tid >> 4;
    float acc[4][4] = {{0.f}};
    for (int p = 0; p < 64; ++p) {
      float4 a4 = *(const float4*)&shA[p * 68 + ty * 4];
      float4 b4 = *(const float4*)&shA[p * 68 + tx * 4];
      float av[4] = {a4.x, a4.y, a4.z, a4.w};
      float bv[4] = {b4.x, b4.y, b4.z, b4.w};
#pragma unroll
      for (int i = 0; i < 4; ++i)
#pragma unroll
        for (int jj = 0; jj < 4; ++jj) acc[i][jj] += av[i] * bv[jj];
    }
    // updated diag tile -> shB (row-major, stride 68)
#pragma unroll
    for (int i = 0; i < 4; ++i) {
      const float* gp = G + (size_t)(D0 + ty * 4 + i) * Q + D0 + tx * 4;
      float4 g = *(const float4*)gp;
      float4 o;
      o.x = g.x - acc[i][0]; o.y = g.y - acc[i][1];
      o.z = g.z - acc[i][2]; o.w = g.w - acc[i][3];
      *(float4*)&shB[(ty * 4 + i) * 68 + tx * 4] = o;
    }
    __syncthreads();
    if (tid < 64) {
      int lane = tid;
      float rr[64];
#pragma unroll
      for (int k4 = 0; k4 < 16; ++k4) {
        float4 v = *(const float4*)&shB[lane * 68 + k4 * 4];
        rr[k4 * 4 + 0] = v.x; rr[k4 * 4 + 1] = v.y;
        rr[k4 * 4 + 2] = v.z; rr[k4 * 4 + 3] = v.w;
      }
      float dv = chol64_reg(rr, lane);
#pragma unroll
      for (int k4 = 0; k4 < 16; ++k4) {
        float4 st;
        st.x = rr[k4 * 4 + 0]; st.y = rr[k4 * 4 + 1];
        st.z = rr[k4 * 4 + 2]; st.w = rr[k4 * 4 + 3];
        *(float4*)(dstage + lane * 64 + k4 * 4) = st;
      }
      float lg = logf(dv);
#pragma unroll
      for (int o = 32; o > 0; o >>= 1) lg += __shfl_down(lg, o);
      if (lane == 0) atomicAdd(&scal[3], lg);
    }
  } else if (bx < ntri) {
    int job = bx;
    int bi = (int)((sqrtf(8.0f * (float)job + 1.0f) - 1.0f) * 0.5f);
    while ((bi + 1) * (bi + 2) / 2 <= job) ++bi;
    while (bi * (bi + 1) / 2 > job) --bi;
    int bk = job - bi * (bi + 1) / 2;
    syrk_tile(G, j0, j0 + 64 + bi * 64, j0 + 64 + bk * 64, shA, shB);
  } else {
    int bk = bx - ntri;
    int C0 = j0 + 64 + bk * 64;
    if (tid < 64) z1s[tid] = z[j0 + tid];
    __syncthreads();
    int rw = tid >> 2, part = tid & 3;
    const float* Lr = G + (size_t)(C0 + rw) * Q + j0;
    float ssum = 0.f;
    for (int p = part; p < 64; p += 4) ssum += Lr[p] * z1s[p];
    ssum += __shfl_down(ssum, 2);
    ssum += __shfl_down(ssum, 1);
    if (part == 0) z[C0 + rw] -= ssum;
  }
}

// ---------------------------------------------------------------------------
__global__ __launch_bounds__(256) void final_assemble(
    const float* __restrict__ z, const float* __restrict__ scal,
    const float* __restrict__ s2e_p, const float* __restrict__ s2b_p,
    float* __restrict__ out) {
  __shared__ float red[4];
  int tid = threadIdx.x;
  float bv = 0.f;
  for (int i = tid; i < Q; i += 256) {
    float zi = z[i];
    bv += zi * zi;
  }
  float bvs = block_sum256(bv, red);
  if (tid == 0) {
    float s2e = s2e_p[0], s2b = s2b_p[0];
    float sig2 = s2e + s2b;
    float c = s2e / sig2;
    float slp = scal[0], mtm = scal[1];
    float tw = scal[2], sl = scal[3];
    float tty = (tw - bvs) / c;          // t' y
    float mrm = (mtm - tty) / c;         // m' R^{-1} m
    float logdetR = (float)(NOBS - Q) * logf(c) + 2.0f * sl;
    out[0] = 0.5f * logdetR + 0.5f * mrm - 0.5f * mtm + 0.5f * slp;
  }
}

// ---------------------------------------------------------------------------
extern "C" void kernel_launch(void* const* d_in, const int* in_sizes, int n_in,
                              void* d_out, int out_size, void* d_ws, size_t ws_size,
                              hipStream_t stream) {
  const float* yt   = (const float*)d_in[0];
  const float* yp   = (const float*)d_in[1];
  const int*   zidx = (const int*)d_in[2];
  const float* dist = (const float*)d_in[3];
  const float* s2e  = (const float*)d_in[4];
  const float* s2b  = (const float*)d_in[5];
  const float* ell  = (const float*)d_in[6];

  float* ws   = (float*)d_ws;
  float* G    = ws;                         // Q*Q floats = 16 MB
  float* z    = ws + (size_t)Q * Q;         // Q
  float* t    = z + Q;                      // Q
  int*   cnt  = (int*)(t + Q);              // Q ints
  float* scal = t + 2 * Q;                  // 8: slp, mtm, tw, sumlogL
  float* dstage = scal + 8;                 // 64*64 staged diag factor

  // zero t, cnt, scal
  hipMemsetAsync(t, 0, (2 * Q + 8) * sizeof(float), stream);

  obs_kernel<<<NOBS / 256, 256, 0, stream>>>(yt, yp, zidx, s2e, s2b, t, cnt, scal);
  build_G<<<(Q * Q) / 256, 256, 0, stream>>>(dist, s2e, s2b, ell, cnt, G);
  matvec_kernel<<<Q, 256, 0, stream>>>(dist, s2e, s2b, ell, cnt, t, z, scal);

  potrf_first<<<1, 64, 0, stream>>>(G, dstage, scal);

  for (int s = 0; s < NSTEPS; ++s) {
    int j0 = s * 64;
    int ntr = Q - j0 - 64;
    int Rtot = ntr + 1;                 // trailing rows + z row
    int nb = ntr >> 6;
    trsm_step<<<(Rtot + 3) / 4, 256, 0, stream>>>(G, z, dstage, j0, Rtot);
    if (nb > 0) {
      int ntri = nb * (nb + 1) / 2;
      syrk_step<<<ntri + nb, 256, 0, stream>>>(G, z, dstage, scal, j0, ntri);
    }
  }

  final_assemble<<<1, 256, 0, stream>>>(z, scal, s2e, s2b, (float*)d_out);
}

// Round 4
// 886.840 us; speedup vs baseline: 7.7733x; 1.2070x over previous
//
#include <hip/hip_runtime.h>
#include <math.h>

#define Q 2048
#define NOBS 8192
#define NSTEPS 32

// ---------------------------------------------------------------------------
// readlane broadcast: lane index is a compile-time literal after unrolling,
// so this is a VALU->SGPR read (no LDS/ds_bpermute 120cy latency).
__device__ __forceinline__ float rl(float v, int l) {
  return __int_as_float(__builtin_amdgcn_readlane(__float_as_int(v), l));
}

// ---------------------------------------------------------------------------
__device__ __forceinline__ float block_sum256(float v, volatile float* red) {
  int tid = threadIdx.x;
#pragma unroll
  for (int o = 32; o > 0; o >>= 1) v += __shfl_down(v, o);
  __syncthreads();
  if ((tid & 63) == 0) red[tid >> 6] = v;
  __syncthreads();
  return red[0] + red[1] + red[2] + red[3];
}

// ---------------------------------------------------------------------------
// In-register 64x64 Cholesky, one wave, lane = row. Broadcasts via readlane.
// Returns lane j's diag sqrt (for logdet). rr[64] MUST stay in VGPRs —
// callers need launch bounds permitting >=~90 VGPRs (spill = 25x slowdown,
// measured round 3: 122us vs ~5us).
__device__ __forceinline__ float chol64_reg(float rr[64], int lane) {
  float dv = 1.0f;
#pragma unroll
  for (int j = 0; j < 64; ++j) {
    float vjj = rl(rr[j], j);
    float invd = rsqrtf(vjj);
    float lij = rr[j] * invd;   // lane j gets sqrt(vjj)
    rr[j] = lij;
    if (lane == j) dv = lij;
#pragma unroll
    for (int k = j + 1; k < 64; ++k) rr[k] -= lij * rl(lij, k);
  }
  return dv;
}

// ---------------------------------------------------------------------------
__global__ __launch_bounds__(256) void obs_kernel(
    const float* __restrict__ yt, const float* __restrict__ yp,
    const int* __restrict__ zidx, const float* __restrict__ s2e_p,
    const float* __restrict__ s2b_p, float* __restrict__ t,
    int* __restrict__ cnt, float* __restrict__ scal) {
  __shared__ float red[4];
  int i = blockIdx.x * 256 + threadIdx.x;
  float s2e = s2e_p[0], s2b = s2b_p[0];
  float sig2 = s2e + s2b;
  float r = yt[i] - yp[i];
  float e = erff(r * rsqrtf(2.0f * sig2));
  float u = 0.5f * (e + 1.0f);
  u = fminf(fmaxf(u, 1e-5f), 1.0f - 1e-5f);
  float m = erfinvf(2.0f * u - 1.0f) * 1.4142135623730951f;
  float slp = -0.5f * logf(2.0f * 3.14159265358979f * sig2) - r * r / (2.0f * sig2);
  int z = zidx[i];
  atomicAdd(&t[z], m);
  atomicAdd(&cnt[z], 1);
  float s1 = block_sum256(slp, red);
  float s2 = block_sum256(m * m, red);
  if (threadIdx.x == 0) {
    atomicAdd(&scal[0], s1);   // sum_log_pdf
    atomicAdd(&scal[1], s2);   // m'm
  }
}

// ---------------------------------------------------------------------------
__global__ __launch_bounds__(256) void build_G(
    const float* __restrict__ dist, const float* __restrict__ s2e_p,
    const float* __restrict__ s2b_p, const float* __restrict__ ell_p,
    const int* __restrict__ cnt, float* __restrict__ G) {
  int idx = blockIdx.x * 256 + threadIdx.x;
  int j = idx >> 11;
  int k = idx & (Q - 1);
  float s2e = s2e_p[0], s2b = s2b_p[0], ell = ell_p[0];
  float sig2 = s2e + s2b;
  float a = (s2b / sig2) * expf(-dist[idx] / (2.0f * ell));
  float g = sqrtf((float)cnt[j] * (float)cnt[k]) * a;
  if (j == k) g += s2e / sig2;
  G[idx] = g;
}

// ---------------------------------------------------------------------------
__global__ __launch_bounds__(256) void matvec_kernel(
    const float* __restrict__ dist, const float* __restrict__ s2e_p,
    const float* __restrict__ s2b_p, const float* __restrict__ ell_p,
    const int* __restrict__ cnt, const float* __restrict__ t,
    float* __restrict__ z, float* __restrict__ scal) {
  __shared__ float red[4];
  int j = blockIdx.x;
  float s2e = s2e_p[0], s2b = s2b_p[0], ell = ell_p[0];
  float sig2 = s2e + s2b;
  float inv2ell = 1.0f / (2.0f * ell);
  float s = 0.0f;
  const float* drow = dist + (size_t)j * Q;
  for (int k = threadIdx.x; k < Q; k += 256) s += expf(-drow[k] * inv2ell) * t[k];
  float tot = block_sum256(s, red);
  if (threadIdx.x == 0) {
    float wj = (s2b / sig2) * tot;
    z[j] = sqrtf((float)cnt[j]) * wj;   // b = W^{1/2} w
    atomicAdd(&scal[2], t[j] * wj);     // t.w
  }
}

// ---------------------------------------------------------------------------
// Factor the first 64x64 diag tile of G into dstage; accumulate logdet.
// __launch_bounds__(64, 1): single wave, full VGPR budget — keeps rr[64]
// in registers (round-3 measured: default bounds -> VGPR=48 -> scratch
// spill -> 122us for a ~5us factor).
__global__ __launch_bounds__(64, 1) void potrf_first(
    const float* __restrict__ G, float* __restrict__ dstage,
    float* __restrict__ scal) {
  int lane = threadIdx.x;
  float rr[64];
  const float* row = G + (size_t)lane * Q;
#pragma unroll
  for (int k4 = 0; k4 < 16; ++k4) {
    float4 v = *(const float4*)(row + k4 * 4);
    rr[k4 * 4 + 0] = v.x; rr[k4 * 4 + 1] = v.y;
    rr[k4 * 4 + 2] = v.z; rr[k4 * 4 + 3] = v.w;
  }
  float dv = chol64_reg(rr, lane);
#pragma unroll
  for (int k4 = 0; k4 < 16; ++k4) {
    float4 st;
    st.x = rr[k4 * 4 + 0]; st.y = rr[k4 * 4 + 1];
    st.z = rr[k4 * 4 + 2]; st.w = rr[k4 * 4 + 3];
    *(float4*)(dstage + lane * 64 + k4 * 4) = st;
  }
  float lg = logf(dv);
#pragma unroll
  for (int o = 32; o > 0; o >>= 1) lg += __shfl_down(lg, o);
  if (lane == 0) atomicAdd(&scal[3], lg);
}

// ---------------------------------------------------------------------------
// TRSM of the panel below the staged diag factor (+ z as a virtual row).
// One row per wave; readlane-based solve (serial chain ~64 x ~20cy).
__global__ __launch_bounds__(256) void trsm_step(
    float* __restrict__ G, float* __restrict__ z,
    const float* __restrict__ dstage, int j0, int Rtot) {
  __shared__ float shA[64 * 65];
  int tid = threadIdx.x;
#pragma unroll
  for (int it = 0; it < 4; ++it) {
    int idx = it * 256 + tid;          // 1024 chunks of 4 floats
    int r = idx >> 4, c = (idx & 15) * 4;
    float4 v = *(const float4*)(dstage + r * 64 + c);
    shA[r * 65 + c + 0] = v.x; shA[r * 65 + c + 1] = v.y;
    shA[r * 65 + c + 2] = v.z; shA[r * 65 + c + 3] = v.w;
  }
  __syncthreads();
  int lane = tid & 63, wv = tid >> 6;
  int ri = blockIdx.x * 4 + wv;
  if (ri >= Rtot) return;
  int r = j0 + 64 + ri;
  float* grow = (r < Q) ? (G + (size_t)r * Q + j0) : (z + j0);
  float a = grow[lane];
  float myinv = 1.0f / shA[lane * 65 + lane];
#pragma unroll
  for (int p = 0; p < 64; ++p) {
    float xp = rl(a, p) * rl(myinv, p);
    if (lane > p) a -= xp * shA[lane * 65 + p];
  }
  grow[lane] = a * myinv;
}

// ---------------------------------------------------------------------------
// One 64x64 trailing-update tile: G[R0:,C0:] -= P * Qt^T (panel at col j0).
__device__ __forceinline__ void syrk_tile(float* __restrict__ G, int j0,
                                          int R0, int C0, float* shA,
                                          float* shB) {
  int tid = threadIdx.x;
#pragma unroll
  for (int it = 0; it < 4; ++it) {
    int idx = it * 256 + tid;           // 1024 16B chunks
    int r = idx >> 4, c4 = (idx & 15) * 4;
    float4 v = *(const float4*)(G + (size_t)(R0 + r) * Q + j0 + c4);
    shA[(c4 + 0) * 68 + r] = v.x; shA[(c4 + 1) * 68 + r] = v.y;
    shA[(c4 + 2) * 68 + r] = v.z; shA[(c4 + 3) * 68 + r] = v.w;
    float4 u = *(const float4*)(G + (size_t)(C0 + r) * Q + j0 + c4);
    shB[(c4 + 0) * 68 + r] = u.x; shB[(c4 + 1) * 68 + r] = u.y;
    shB[(c4 + 2) * 68 + r] = u.z; shB[(c4 + 3) * 68 + r] = u.w;
  }
  __syncthreads();
  int tx = tid & 15, ty = tid >> 4;
  float acc[4][4] = {{0.f}};
  for (int p = 0; p < 64; ++p) {
    float4 a4 = *(const float4*)&shA[p * 68 + ty * 4];
    float4 b4 = *(const float4*)&shB[p * 68 + tx * 4];
    float av[4] = {a4.x, a4.y, a4.z, a4.w};
    float bv[4] = {b4.x, b4.y, b4.z, b4.w};
#pragma unroll
    for (int i = 0; i < 4; ++i)
#pragma unroll
      for (int jj = 0; jj < 4; ++jj) acc[i][jj] += av[i] * bv[jj];
  }
#pragma unroll
  for (int i = 0; i < 4; ++i) {
    float* gp = G + (size_t)(R0 + ty * 4 + i) * Q + C0 + tx * 4;
    float4 g = *(const float4*)gp;
    g.x -= acc[i][0]; g.y -= acc[i][1];
    g.z -= acc[i][2]; g.w -= acc[i][3];
    *(float4*)gp = g;
  }
}

// ---------------------------------------------------------------------------
// Per-step trailing work, one job per block:
//   job 0            : lookahead — update NEXT diag tile and factor it into
//                      dstage (never written back to G; not needed again).
//   job in [1,ntri)  : strict-lower / off-diag trailing SYRK tiles.
//   job in [ntri, ..): z forward-substitution updates per trailing block.
// __launch_bounds__(256, 1): spill guard for the block-0 chol path (rr[64]
// must stay in VGPRs; LDS already caps occupancy at 4 blocks/CU).
__global__ __launch_bounds__(256, 1) void syrk_step(
    float* __restrict__ G, float* __restrict__ z, float* __restrict__ dstage,
    float* __restrict__ scal, int j0, int ntri) {
  __shared__ __align__(16) float shA[64 * 68];
  __shared__ __align__(16) float shB[64 * 68];
  __shared__ float z1s[64];
  int tid = threadIdx.x;
  int bx = blockIdx.x;

  if (bx == 0) {
    int D0 = j0 + 64;
    // stage panel rows D0..D0+64, cols j0..j0+64 (transposed) into shA
#pragma unroll
    for (int it = 0; it < 4; ++it) {
      int idx = it * 256 + tid;
      int r2 = idx >> 4, c4 = (idx & 15) * 4;
      float4 v = *(const float4*)(G + (size_t)(D0 + r2) * Q + j0 + c4);
      shA[(c4 + 0) * 68 + r2] = v.x; shA[(c4 + 1) * 68 + r2] = v.y;
      shA[(c4 + 2) * 68 + r2] = v.z; shA[(c4 + 3) * 68 + r2] = v.w;
    }
    __syncthreads();
    int tx = tid & 15, ty = tid >> 4;
    float acc[4][4] = {{0.f}};
    for (int p = 0; p < 64; ++p) {
      float4 a4 = *(const float4*)&shA[p * 68 + ty * 4];
      float4 b4 = *(const float4*)&shA[p * 68 + tx * 4];
      float av[4] = {a4.x, a4.y, a4.z, a4.w};
      float bv[4] = {b4.x, b4.y, b4.z, b4.w};
#pragma unroll
      for (int i = 0; i < 4; ++i)
#pragma unroll
        for (int jj = 0; jj < 4; ++jj) acc[i][jj] += av[i] * bv[jj];
    }
    // updated diag tile -> shB (row-major, stride 68)
#pragma unroll
    for (int i = 0; i < 4; ++i) {
      const float* gp = G + (size_t)(D0 + ty * 4 + i) * Q + D0 + tx * 4;
      float4 g = *(const float4*)gp;
      float4 o;
      o.x = g.x - acc[i][0]; o.y = g.y - acc[i][1];
      o.z = g.z - acc[i][2]; o.w = g.w - acc[i][3];
      *(float4*)&shB[(ty * 4 + i) * 68 + tx * 4] = o;
    }
    __syncthreads();
    if (tid < 64) {
      int lane = tid;
      float rr[64];
#pragma unroll
      for (int k4 = 0; k4 < 16; ++k4) {
        float4 v = *(const float4*)&shB[lane * 68 + k4 * 4];
        rr[k4 * 4 + 0] = v.x; rr[k4 * 4 + 1] = v.y;
        rr[k4 * 4 + 2] = v.z; rr[k4 * 4 + 3] = v.w;
      }
      // Serial latency-critical chain sharing the CU with tile blocks:
      // raise wave priority so the scheduler favors it (T5 regime).
      __builtin_amdgcn_s_setprio(1);
      float dv = chol64_reg(rr, lane);
      __builtin_amdgcn_s_setprio(0);
#pragma unroll
      for (int k4 = 0; k4 < 16; ++k4) {
        float4 st;
        st.x = rr[k4 * 4 + 0]; st.y = rr[k4 * 4 + 1];
        st.z = rr[k4 * 4 + 2]; st.w = rr[k4 * 4 + 3];
        *(float4*)(dstage + lane * 64 + k4 * 4) = st;
      }
      float lg = logf(dv);
#pragma unroll
      for (int o = 32; o > 0; o >>= 1) lg += __shfl_down(lg, o);
      if (lane == 0) atomicAdd(&scal[3], lg);
    }
  } else if (bx < ntri) {
    int job = bx;
    int bi = (int)((sqrtf(8.0f * (float)job + 1.0f) - 1.0f) * 0.5f);
    while ((bi + 1) * (bi + 2) / 2 <= job) ++bi;
    while (bi * (bi + 1) / 2 > job) --bi;
    int bk = job - bi * (bi + 1) / 2;
    syrk_tile(G, j0, j0 + 64 + bi * 64, j0 + 64 + bk * 64, shA, shB);
  } else {
    int bk = bx - ntri;
    int C0 = j0 + 64 + bk * 64;
    if (tid < 64) z1s[tid] = z[j0 + tid];
    __syncthreads();
    int rw = tid >> 2, part = tid & 3;
    const float* Lr = G + (size_t)(C0 + rw) * Q + j0;
    float ssum = 0.f;
    for (int p = part; p < 64; p += 4) ssum += Lr[p] * z1s[p];
    ssum += __shfl_down(ssum, 2);
    ssum += __shfl_down(ssum, 1);
    if (part == 0) z[C0 + rw] -= ssum;
  }
}

// ---------------------------------------------------------------------------
__global__ __launch_bounds__(256) void final_assemble(
    const float* __restrict__ z, const float* __restrict__ scal,
    const float* __restrict__ s2e_p, const float* __restrict__ s2b_p,
    float* __restrict__ out) {
  __shared__ float red[4];
  int tid = threadIdx.x;
  float bv = 0.f;
  for (int i = tid; i < Q; i += 256) {
    float zi = z[i];
    bv += zi * zi;
  }
  float bvs = block_sum256(bv, red);
  if (tid == 0) {
    float s2e = s2e_p[0], s2b = s2b_p[0];
    float sig2 = s2e + s2b;
    float c = s2e / sig2;
    float slp = scal[0], mtm = scal[1];
    float tw = scal[2], sl = scal[3];
    float tty = (tw - bvs) / c;          // t' y
    float mrm = (mtm - tty) / c;         // m' R^{-1} m
    float logdetR = (float)(NOBS - Q) * logf(c) + 2.0f * sl;
    out[0] = 0.5f * logdetR + 0.5f * mrm - 0.5f * mtm + 0.5f * slp;
  }
}

// ---------------------------------------------------------------------------
extern "C" void kernel_launch(void* const* d_in, const int* in_sizes, int n_in,
                              void* d_out, int out_size, void* d_ws, size_t ws_size,
                              hipStream_t stream) {
  const float* yt   = (const float*)d_in[0];
  const float* yp   = (const float*)d_in[1];
  const int*   zidx = (const int*)d_in[2];
  const float* dist = (const float*)d_in[3];
  const float* s2e  = (const float*)d_in[4];
  const float* s2b  = (const float*)d_in[5];
  const float* ell  = (const float*)d_in[6];

  float* ws   = (float*)d_ws;
  float* G    = ws;                         // Q*Q floats = 16 MB
  float* z    = ws + (size_t)Q * Q;         // Q
  float* t    = z + Q;                      // Q
  int*   cnt  = (int*)(t + Q);              // Q ints
  float* scal = t + 2 * Q;                  // 8: slp, mtm, tw, sumlogL
  float* dstage = scal + 8;                 // 64*64 staged diag factor

  // zero t, cnt, scal
  hipMemsetAsync(t, 0, (2 * Q + 8) * sizeof(float), stream);

  obs_kernel<<<NOBS / 256, 256, 0, stream>>>(yt, yp, zidx, s2e, s2b, t, cnt, scal);
  build_G<<<(Q * Q) / 256, 256, 0, stream>>>(dist, s2e, s2b, ell, cnt, G);
  matvec_kernel<<<Q, 256, 0, stream>>>(dist, s2e, s2b, ell, cnt, t, z, scal);

  potrf_first<<<1, 64, 0, stream>>>(G, dstage, scal);

  for (int s = 0; s < NSTEPS; ++s) {
    int j0 = s * 64;
    int ntr = Q - j0 - 64;
    int Rtot = ntr + 1;                 // trailing rows + z row
    int nb = ntr >> 6;
    trsm_step<<<(Rtot + 3) / 4, 256, 0, stream>>>(G, z, dstage, j0, Rtot);
    if (nb > 0) {
      int ntri = nb * (nb + 1) / 2;
      syrk_step<<<ntri + nb, 256, 0, stream>>>(G, z, dstage, scal, j0, ntri);
    }
  }

  final_assemble<<<1, 256, 0, stream>>>(z, scal, s2e, s2b, (float*)d_out);
}